// Round 6
// baseline (32.916 us; speedup 1.0000x reference)
//
#include <hip/hip_runtime.h>

#define N_NODES 207
#define N_EDGES 1722
#define N_SLOTS 288
#define L_DIM 24            // 2*12 feature channels
#define NPK 12              // packed bf16x2 words per node row (24 ch)
#define TOT_ENT (2 * N_EDGES)

typedef float f32x2 __attribute__((ext_vector_type(2)));

// CDNA packed fp32 math: 2 FMAs / adds per instruction.
__device__ __forceinline__ f32x2 pk_fma(f32x2 a, f32x2 b, f32x2 c) {
    f32x2 d;
    asm("v_pk_fma_f32 %0, %1, %2, %3" : "=v"(d) : "v"(a), "v"(b), "v"(c));
    return d;
}
__device__ __forceinline__ f32x2 pk_add(f32x2 a, f32x2 b) {
    f32x2 d;
    asm("v_pk_add_f32 %0, %1, %2" : "=v"(d) : "v"(a), "v"(b));
    return d;
}
// RNE pack of 2 f32 -> bf16x2 (no builtin on gfx950)
__device__ __forceinline__ unsigned pack_bf16x2(float a, float b) {
    unsigned r;
    asm("v_cvt_pk_bf16_f32 %0, %1, %2" : "=v"(r) : "v"(a), "v"(b));
    return r;
}
// unpack bf16x2 -> f32x2: 2 VALU
__device__ __forceinline__ f32x2 unpack_bf16x2(unsigned u) {
    f32x2 r;
    r.x = __uint_as_float(u << 16);
    r.y = __uint_as_float(u & 0xffff0000u);
    return r;
}
// fast tanh: 1 - 2/(e^{2x}+1); both saturation limits exact.
__device__ __forceinline__ float fast_tanhf(float x) {
    float e2 = __expf(2.0f * x);
    return 1.0f - 2.0f * __builtin_amdgcn_rcpf(e2 + 1.0f);
}

// ---------------------------------------------------------------------------
// Kernel 1: build CSR incidence + degree-descending node permutation.
// Single block, 256 threads, shfl-based scans. Runs once per launch.
// ---------------------------------------------------------------------------
__global__ __launch_bounds__(256) void build_csr_kernel(
    const int* __restrict__ edge_index,     // [2, N_EDGES]
    int* __restrict__ csr_off,              // [N_NODES + 1]
    unsigned int* __restrict__ entries,     // [TOT_ENT + 4], nbr | (edge<<16)
    int* __restrict__ perm)                 // [N_NODES] degree-desc node order
{
    __shared__ int cnt[N_NODES];
    __shared__ int cursor[N_NODES];
    __shared__ int wsum[4];
    __shared__ int dcur[64];     // degree-bucket cursors (counting sort)
    const int tid  = threadIdx.x;
    const int lane = tid & 63;
    const int wid  = tid >> 6;

    if (tid < N_NODES) cnt[tid] = 0;
    if (tid < 64) dcur[tid] = 0;
    __syncthreads();

    for (int e = tid; e < N_EDGES; e += 256) {
        int i = edge_index[e];
        int j = edge_index[N_EDGES + e];
        atomicAdd(&cnt[i], 1);
        atomicAdd(&cnt[j], 1);
    }
    __syncthreads();

    // exclusive scan of degrees over 256 slots via wave shfl-scan
    const int deg = (tid < N_NODES) ? cnt[tid] : 0;
    int x = deg;
    #pragma unroll
    for (int s = 1; s < 64; s <<= 1) {
        int t = __shfl_up(x, s, 64);
        if (lane >= s) x += t;
    }
    if (lane == 63) wsum[wid] = x;
    // degree histogram for counting sort (bucket = min(deg,63))
    int dcap = deg > 63 ? 63 : deg;
    if (tid < N_NODES) atomicAdd(&dcur[dcap], 1);
    __syncthreads();

    int base = 0;
    for (int i = 0; i < wid; ++i) base += wsum[i];
    const int excl = base + x - deg;
    if (tid < N_NODES) { csr_off[tid] = excl; cursor[tid] = excl; }
    if (tid == 255) {
        csr_off[N_NODES] = base + x;
        entries[TOT_ENT]     = 0u;   // sentinels for 2-ahead prefetch
        entries[TOT_ENT + 1] = 0u;
    }

    // descending-degree exclusive offsets: off(d) = #nodes with degree > d
    if (tid < 64) {
        int h = dcur[63 - tid];          // ascending tid = descending degree
        int xs = h;
        #pragma unroll
        for (int s = 1; s < 64; s <<= 1) {
            int t = __shfl_up(xs, s, 64);
            if (lane >= s) xs += t;
        }
        __syncthreads();                 // all reads of dcur done
        dcur[63 - tid] = xs - h;
    } else {
        __syncthreads();
    }
    __syncthreads();

    if (tid < N_NODES) {
        int p = atomicAdd(&dcur[dcap], 1);
        perm[p] = tid;
    }
    __syncthreads();

    for (int e = tid; e < N_EDGES; e += 256) {
        int i = edge_index[e];
        int j = edge_index[N_EDGES + e];
        int pi = atomicAdd(&cursor[i], 1);
        entries[pi] = (unsigned int)j | ((unsigned int)e << 16);
        int pj = atomicAdd(&cursor[j], 1);
        entries[pj] = (unsigned int)i | ((unsigned int)e << 16);
    }
}

// ---------------------------------------------------------------------------
// Kernel 2: fused main kernel. Block = batch element; thread slot tid owns
// node perm[tid]. Gather loop is 2-stage software-pipelined: entry k+2
// issued at iter-k top; entry k+1 (arrived during iter k-1) decoded and its
// weight + 3 x-row b128 reads issued immediately; iter k's FMA body covers
// them. Weights packed bf16x2 (one b32/entry). LDS ~30.6 KB -> 4 blocks/CU.
// ---------------------------------------------------------------------------
__global__ __launch_bounds__(256, 4) void rdgcn_main_kernel(
    const float* __restrict__ x_in,      // [B, 24, 207] (l-major)
    const float* __restrict__ w_react,   // [N_SLOTS, N_EDGES]
    const float* __restrict__ w_diff,    // [N_SLOTS, N_EDGES]
    const float* __restrict__ b_react,   // [N_SLOTS, N_NODES]
    const float* __restrict__ b_diff,    // [N_SLOTS, N_NODES]
    const float* __restrict__ w_self,    // [N_SLOTS, N_NODES]
    const int* __restrict__ ind,         // [B]
    const int* __restrict__ csr_off,     // [N_NODES + 1]
    const unsigned int* __restrict__ entries, // [TOT_ENT + 4] (2 sentinels)
    const int* __restrict__ perm,        // [N_NODES]
    float* __restrict__ out)             // [B, 207, 24]
{
    __shared__ unsigned x_sh[N_NODES * NPK];   // 9936 B, 48 B rows
    __shared__ unsigned wrd_sh[N_EDGES];       // 6888 B, bf16x2 (wr, wd)
    __shared__ unsigned ent_sh[TOT_ENT + 4];   // 13792 B  (total ~30.6 KB)

    const int b   = blockIdx.x;
    const int tid = threadIdx.x;
    const int s   = ind[b];   // RESOLUTION == 1

    // Hoist all per-thread scalar loads to the very top — their latency
    // hides under the staging phase.
    int w = 0, beg = 0, end = 0;
    float br = 0.f, bd = 0.f, wsl = 0.f;
    if (tid < N_NODES) {
        w   = perm[tid];
        beg = csr_off[w];
        end = csr_off[w + 1];
        br  = b_react[s * N_NODES + w];
        bd  = b_diff [s * N_NODES + w];
        wsl = w_self [s * N_NODES + w];
    }

    // Stage entries: uint4 coalesced (TOT_ENT = 3444 = 861*4) + sentinels.
    {
        const uint4* eg4 = reinterpret_cast<const uint4*>(entries);
        uint4* es4 = reinterpret_cast<uint4*>(ent_sh);
        for (int k = tid; k < TOT_ENT / 4; k += 256) es4[k] = eg4[k];
        if (tid == 0) { ent_sh[TOT_ENT] = 0u; ent_sh[TOT_ENT + 1] = 0u; }
    }
    // Stage x: thread v gathers node row v (coalesced across lanes per l),
    // packs to bf16x2, writes 3 x b128.
    const float* xg = x_in + (size_t)b * (N_NODES * L_DIM);
    if (tid < N_NODES) {
        float row[L_DIM];
        #pragma unroll
        for (int l = 0; l < L_DIM; ++l) row[l] = xg[l * N_NODES + tid];
        unsigned pk[NPK];
        #pragma unroll
        for (int i = 0; i < NPK; ++i) pk[i] = pack_bf16x2(row[2*i], row[2*i+1]);
        uint4* dst = reinterpret_cast<uint4*>(&x_sh[tid * NPK]);
        dst[0] = make_uint4(pk[0], pk[1], pk[2],  pk[3]);
        dst[1] = make_uint4(pk[4], pk[5], pk[6],  pk[7]);
        dst[2] = make_uint4(pk[8], pk[9], pk[10], pk[11]);
    }
    // Stage this slot's edge weights as packed bf16x2 (one b32 per entry).
    {
        const float* wrg = w_react + (size_t)s * N_EDGES;
        const float* wdg = w_diff  + (size_t)s * N_EDGES;
        for (int e = tid; e < N_EDGES; e += 256)
            wrd_sh[e] = pack_bf16x2(wrg[e], wdg[e]);
    }
    __syncthreads();

    if (tid >= N_NODES) return;

    f32x2 accr[NPK], accd[NPK];
    #pragma unroll
    for (int i = 0; i < NPK; ++i) { accr[i] = (f32x2)0.f; accd[i] = (f32x2)0.f; }
    f32x2 sw2 = (f32x2)0.f;      // (d_r[w], d_d[w]) running degree sums

    // ---- 2-stage pipeline prologue ----
    unsigned enB = ent_sh[beg];          // entry for iter "k" slot
    unsigned enN = ent_sh[beg + 1];      // entry one ahead (sentinel-safe)
    {
        const int nbr0 = (int)(enB & 0xffffu);
        const int e0   = (int)(enB >> 16);
        const unsigned wvu = wrd_sh[e0];
        const uint4* xr0 = reinterpret_cast<const uint4*>(&x_sh[nbr0 * NPK]);
        uint4 qa = xr0[0], qb = xr0[1], qc = xr0[2];
        f32x2 wv0 = unpack_bf16x2(wvu);
        enB = enN;

        for (int k = beg; k < end; ++k) {
            // --- stage k+1: issue all its LDS loads now ---
            const unsigned enC = ent_sh[k + 2];          // 2-ahead entry
            const int nbr1 = (int)(enB & 0xffffu);       // enB arrived last iter
            const int e1   = (int)(enB >> 16);
            const unsigned wv1u = wrd_sh[e1];
            const uint4* xr1 = reinterpret_cast<const uint4*>(&x_sh[nbr1 * NPK]);
            const uint4 ra = xr1[0], rb = xr1[1], rc = xr1[2];
            // --- consume k (data has been in flight a full body) ---
            sw2 = pk_add(sw2, wv0);
            f32x2 wr2; wr2.x = wv0.x; wr2.y = wv0.x;
            f32x2 wd2; wd2.x = wv0.y; wd2.y = wv0.y;
            #define RD_STEP(u, i) { \
                const f32x2 xv = unpack_bf16x2(u); \
                accr[i] = pk_fma(wr2, xv, accr[i]); \
                accd[i] = pk_fma(wd2, xv, accd[i]); }
            RD_STEP(qa.x, 0)  RD_STEP(qa.y, 1)  RD_STEP(qa.z, 2)  RD_STEP(qa.w, 3)
            RD_STEP(qb.x, 4)  RD_STEP(qb.y, 5)  RD_STEP(qb.z, 6)  RD_STEP(qb.w, 7)
            RD_STEP(qc.x, 8)  RD_STEP(qc.y, 9)  RD_STEP(qc.z, 10) RD_STEP(qc.w, 11)
            #undef RD_STEP
            // --- rotate ---
            enB = enC;
            wv0 = unpack_bf16x2(wv1u);
            qa = ra; qb = rb; qc = rc;
        }
    }

    const float swr = sw2.x, swd = sw2.y;
    // Own row re-read from LDS post-loop (keeps loop register pressure low).
    const uint4* xw = reinterpret_cast<const uint4*>(&x_sh[w * NPK]);
    float* op = out + (size_t)b * (N_NODES * L_DIM) + (size_t)w * L_DIM;
    #pragma unroll
    for (int c = 0; c < 3; ++c) {
        const uint4 q = xw[c];
        float4 o0, o1;
        #define EP_STEP(u, j, oa, ob) { \
            const f32x2 xv = unpack_bf16x2(u); \
            float re = fmaf(swr, xv.x,  accr[j].x) + br; \
            float di = fmaf(swd, xv.x, -accd[j].x) + bd; \
            oa = fast_tanhf(re) + di + fmaf(xv.x, wsl, xv.x); \
            re = fmaf(swr, xv.y,  accr[j].y) + br; \
            di = fmaf(swd, xv.y, -accd[j].y) + bd; \
            ob = fast_tanhf(re) + di + fmaf(xv.y, wsl, xv.y); }
        EP_STEP(q.x, 4*c + 0, o0.x, o0.y)
        EP_STEP(q.y, 4*c + 1, o0.z, o0.w)
        EP_STEP(q.z, 4*c + 2, o1.x, o1.y)
        EP_STEP(q.w, 4*c + 3, o1.z, o1.w)
        #undef EP_STEP
        reinterpret_cast<float4*>(op)[2*c]     = o0;
        reinterpret_cast<float4*>(op)[2*c + 1] = o1;
    }
}

extern "C" void kernel_launch(void* const* d_in, const int* in_sizes, int n_in,
                              void* d_out, int out_size, void* d_ws, size_t ws_size,
                              hipStream_t stream) {
    const float* x_in     = (const float*)d_in[0];
    const float* w_react  = (const float*)d_in[1];
    const float* w_diff   = (const float*)d_in[2];
    const float* b_react  = (const float*)d_in[3];
    const float* b_diff   = (const float*)d_in[4];
    const float* w_self   = (const float*)d_in[5];
    const int*   ind      = (const int*)d_in[6];
    const int*   edge_idx = (const int*)d_in[7];
    float* out = (float*)d_out;

    // ws layout: csr_off [208 ints] | entries [TOT_ENT+4 u32] | perm [256 ints]
    char* wp = (char*)d_ws;
    int* csr_off = (int*)wp;
    wp += (((size_t)(N_NODES + 1) * sizeof(int)) + 255) & ~(size_t)255;
    unsigned int* entries = (unsigned int*)wp;
    wp += (((size_t)(TOT_ENT + 4) * sizeof(unsigned int)) + 255) & ~(size_t)255;
    int* perm = (int*)wp;

    build_csr_kernel<<<1, 256, 0, stream>>>(edge_idx, csr_off, entries, perm);

    const int B = in_sizes[6];   // 1024
    rdgcn_main_kernel<<<B, 256, 0, stream>>>(x_in, w_react, w_diff,
                                             b_react, b_diff, w_self,
                                             ind, csr_off, entries, perm, out);
}